// Round 5
// baseline (853.169 us; speedup 1.0000x reference)
//
#include <hip/hip_runtime.h>
#include <hip/hip_bf16.h>
#include <cstdint>
#include <cstddef>

#define KD 512
#define BK 32

// ---- workspace byte offsets ----
#define OFF_CN   0u           // 4096 f32 coarse codebook norms
#define OFF_FN   16384u       // 8192 f32 fine codebook norms
#define OFF_ZN   49152u       // 8192 f32 z-coarse row norms
#define OFF_RN   81920u       // 8192 f32 residual row norms
#define OFF_LOSS 114688u      // 1 f32 loss accumulator
#define OFF_AMC  114944u      // 8192 u64 coarse argmin keys
#define OFF_AMF  180480u      // 8192 u64 fine argmin keys
#define OFF_CEH  246016u      // 4096x512 bf16
#define OFF_CEL  4440320u
#define OFF_FEH  8634624u     // 8192x512 bf16
#define OFF_FEL  17023232u
#define OFF_ZCH  25411840u    // 8192x512 bf16
#define OFF_ZCL  33800448u
#define OFF_RH   42189056u    // 8192x512 bf16 residual
#define OFF_RL   50577664u
#define OFF_W1H  58966272u    // 512x512 bf16
#define OFF_W1L  59490560u
#define OFF_W2H  60014848u
#define OFF_W2L  60539136u
#define OFF_H    61063424u    // 8192x512 f32
#define OFF_INFL 77840640u    // 8192x512 bf16
// total = 86,229,248 bytes

typedef __attribute__((ext_vector_type(8))) short bf16x8;
typedef __attribute__((ext_vector_type(4))) float f32x4;

__device__ __forceinline__ bf16x8 as_bf16x8(int4 v) {
  union { int4 i; bf16x8 b; } u; u.i = v; return u.b;
}

__device__ __forceinline__ float block_sum(float v, float* sred) {
#pragma unroll
  for (int off = 32; off > 0; off >>= 1) v += __shfl_down(v, off, 64);
  if ((threadIdx.x & 63) == 0) sred[threadIdx.x >> 6] = v;
  __syncthreads();
  float r = sred[0] + sred[1] + sred[2] + sred[3];
  __syncthreads();
  return r;
}

__device__ __forceinline__ float sigmoidf_(float x) { return 1.0f / (1.0f + expf(-x)); }

__device__ __forceinline__ void split_bf16(float v, __hip_bfloat16* hi, __hip_bfloat16* lo) {
  __hip_bfloat16 h = __float2bfloat16(v);
  *hi = h;
  *lo = __float2bfloat16(v - __bfloat162float(h));
}

// ---- prep: norms + hi/lo split for ce / fe / z-coarse / w1 / w2 ----
__global__ __launch_bounds__(256) void prep(
    const float* __restrict__ ce, const float* __restrict__ fe, const float* __restrict__ z,
    const float* __restrict__ w1, const float* __restrict__ w2,
    float* __restrict__ cn, float* __restrict__ fn, float* __restrict__ zn,
    __hip_bfloat16* __restrict__ ceH, __hip_bfloat16* __restrict__ ceL,
    __hip_bfloat16* __restrict__ feH, __hip_bfloat16* __restrict__ feL,
    __hip_bfloat16* __restrict__ zcH, __hip_bfloat16* __restrict__ zcL,
    __hip_bfloat16* __restrict__ w1H, __hip_bfloat16* __restrict__ w1L,
    __hip_bfloat16* __restrict__ w2H, __hip_bfloat16* __restrict__ w2L,
    float* __restrict__ lossp) {
  __shared__ float sred[4];
  const int b = blockIdx.x, t = threadIdx.x;
  const float* src;
  float* nd = nullptr;
  __hip_bfloat16 *dh, *dl;
  size_t row;
  if (b < 4096) {
    row = b; src = ce + row * KD; nd = cn + row; dh = ceH; dl = ceL;
  } else if (b < 12288) {
    row = b - 4096; src = fe + row * KD; nd = fn + row; dh = feH; dl = feL;
  } else if (b < 20480) {
    row = b - 12288; src = z + row * 1024; nd = zn + row; dh = zcH; dl = zcL;
  } else if (b < 20992) {
    row = b - 20480; src = w1 + row * KD; dh = w1H; dl = w1L;
  } else {
    row = b - 20992; src = w2 + row * KD; dh = w2H; dl = w2L;
  }
  float acc = 0.0f;
#pragma unroll
  for (int j = 0; j < 2; ++j) {
    int c = t + j * 256;
    float v = src[c];
    acc += v * v;
    __hip_bfloat16 h, l;
    split_bf16(v, &h, &l);
    dh[row * KD + c] = h;
    dl[row * KD + c] = l;
  }
  if (nd) {
    float s = block_sum(acc, sred);
    if (t == 0) nd[0] = s;
  }
  if (b == 20480 && t == 0) lossp[0] = 0.0f;
}

// ---- bf16x3 MFMA GEMM: A frags direct-from-global (prefetched), B in LDS ----
// dot = Ah*Bh + Ah*Bl + Al*Bh (fp32 accum). eMode 0: argmin; 1: store+bias.
__global__ __launch_bounds__(256) void gemm5(
    const __hip_bfloat16* __restrict__ Ah, const __hip_bfloat16* __restrict__ Al,
    const unsigned long long* __restrict__ gather,
    const __hip_bfloat16* __restrict__ Bh, const __hip_bfloat16* __restrict__ Bl,
    const float* __restrict__ rowNorm, const float* __restrict__ colNorm,
    unsigned long long* __restrict__ amin,
    const float* __restrict__ bias, float* __restrict__ C, int eMode) {
  __shared__ __align__(16) __hip_bfloat16 sBh[128 * 32];
  __shared__ __align__(16) __hip_bfloat16 sBl[128 * 32];
  const int t = threadIdx.x;
  const int w = t >> 6, l = t & 63;
  const int rowTile = blockIdx.y << 7;
  const int colTile = blockIdx.x << 7;
  const int wr = (w >> 1) << 6;
  const int wc = (w & 1) << 6;

  // B staging: thread t covers B rows srow, srow+64; 16B k-block sb, swizzled
  const int srow = t >> 2;
  const int sb = t & 3;
  const int skE = sb << 3;
  const int swz = (sb ^ ((srow >> 1) & 3)) << 3;
  const int wOff0 = (srow << 5) + swz;
  const int wOff1 = ((srow + 64) << 5) + swz;  // same swz: ((srow+64)>>1)&3 == (srow>>1)&3
  const size_t br0 = (size_t)(colTile + srow) * KD;
  const size_t br1 = (size_t)(colTile + 64 + srow) * KD;

  // A fragment addressing: lane l holds A[row = rowTile+wr+mt*16+(l&15)][k = kk+(l>>4)*8 ..+8]
  const int fr = l & 15;
  const int q = l >> 4;
  const int kOff = q << 3;
  size_t aRow[4];
  if (gather) {
#pragma unroll
    for (int mt = 0; mt < 4; ++mt) {
      unsigned idx = ((const unsigned*)gather)[2 * (rowTile + wr + (mt << 4) + fr)];
      aRow[mt] = (size_t)idx * KD;
    }
  } else {
#pragma unroll
    for (int mt = 0; mt < 4; ++mt) aRow[mt] = (size_t)(rowTile + wr + (mt << 4) + fr) * KD;
  }

  f32x4 acc[4][4];
#pragma unroll
  for (int i = 0; i < 4; ++i)
#pragma unroll
    for (int j = 0; j < 4; ++j) acc[i][j] = (f32x4){0.f, 0.f, 0.f, 0.f};

  // prologue: chunk-0 B staging regs + A fragment regs
  int4 rBh0 = *(const int4*)(Bh + br0 + skE);
  int4 rBh1 = *(const int4*)(Bh + br1 + skE);
  int4 rBl0 = *(const int4*)(Bl + br0 + skE);
  int4 rBl1 = *(const int4*)(Bl + br1 + skE);
  int4 aH[4], aL[4];
#pragma unroll
  for (int mt = 0; mt < 4; ++mt) {
    aH[mt] = *(const int4*)(Ah + aRow[mt] + kOff);
    aL[mt] = *(const int4*)(Al + aRow[mt] + kOff);
  }

  for (int kk = 0; kk < KD; kk += BK) {
    __syncthreads();  // all waves done reading previous chunk's B frags
    *(int4*)(sBh + wOff0) = rBh0; *(int4*)(sBh + wOff1) = rBh1;
    *(int4*)(sBl + wOff0) = rBl0; *(int4*)(sBl + wOff1) = rBl1;
    __syncthreads();  // B staged

    const int nk = (kk + BK < KD) ? kk + BK : 0;  // next chunk (wraps harmlessly)
    // prefetch next B staging regs (latency covered by this chunk's frag+MFMA)
    rBh0 = *(const int4*)(Bh + br0 + nk + skE);
    rBh1 = *(const int4*)(Bh + br1 + nk + skE);
    rBl0 = *(const int4*)(Bl + br0 + nk + skE);
    rBl1 = *(const int4*)(Bl + br1 + nk + skE);

    // current A frags -> operands; prefetch next A frags
    bf16x8 afh[4], afl[4];
#pragma unroll
    for (int mt = 0; mt < 4; ++mt) {
      afh[mt] = as_bf16x8(aH[mt]);
      afl[mt] = as_bf16x8(aL[mt]);
    }
#pragma unroll
    for (int mt = 0; mt < 4; ++mt) {
      aH[mt] = *(const int4*)(Ah + aRow[mt] + nk + kOff);
      aL[mt] = *(const int4*)(Al + aRow[mt] + nk + kOff);
    }

    // B frags from LDS (swizzled, conflict-free)
    bf16x8 bfh[4], bfl[4];
#pragma unroll
    for (int nt = 0; nt < 4; ++nt) {
      const int rB = wc + (nt << 4) + fr;
      const int o = (rB << 5) + ((q ^ ((rB >> 1) & 3)) << 3);
      bfh[nt] = *(const bf16x8*)(sBh + o);
      bfl[nt] = *(const bf16x8*)(sBl + o);
    }
#pragma unroll
    for (int mt = 0; mt < 4; ++mt)
#pragma unroll
      for (int nt = 0; nt < 4; ++nt) {
        acc[mt][nt] = __builtin_amdgcn_mfma_f32_16x16x32_bf16(afh[mt], bfh[nt], acc[mt][nt], 0, 0, 0);
        acc[mt][nt] = __builtin_amdgcn_mfma_f32_16x16x32_bf16(afh[mt], bfl[nt], acc[mt][nt], 0, 0, 0);
        acc[mt][nt] = __builtin_amdgcn_mfma_f32_16x16x32_bf16(afl[mt], bfh[nt], acc[mt][nt], 0, 0, 0);
      }
  }

  const int quad = l >> 4;
  if (eMode == 0) {
    // C/D layout: col = lane&15, row = quad*4 + reg
#pragma unroll
    for (int mt = 0; mt < 4; ++mt) {
#pragma unroll
      for (int reg = 0; reg < 4; ++reg) {
        const int row = rowTile + wr + (mt << 4) + (quad << 2) + reg;
        const float xn = rowNorm[row];
        unsigned long long key = ~0ULL;
#pragma unroll
        for (int nt = 0; nt < 4; ++nt) {
          const int col = colTile + wc + (nt << 4) + fr;
          float d = (xn + colNorm[col]) - 2.0f * acc[mt][nt][reg];
          unsigned ub = __float_as_uint(d);
          ub = (ub & 0x80000000u) ? ~ub : (ub | 0x80000000u);
          unsigned long long k2 = ((unsigned long long)ub << 32) | (unsigned long long)(unsigned)col;
          if (k2 < key) key = k2;
        }
#pragma unroll
        for (int off = 1; off < 16; off <<= 1) {
          unsigned long long o = __shfl_xor(key, off, 64);
          if (o < key) key = o;
        }
        if (fr == 0) atomicMin(amin + row, key);
      }
    }
  } else {
#pragma unroll
    for (int mt = 0; mt < 4; ++mt) {
#pragma unroll
      for (int reg = 0; reg < 4; ++reg) {
        const int row = rowTile + wr + (mt << 4) + (quad << 2) + reg;
#pragma unroll
        for (int nt = 0; nt < 4; ++nt) {
          const int col = colTile + wc + (nt << 4) + fr;
          C[(size_t)row * KD + col] = acc[mt][nt][reg] + bias[col];
        }
      }
    }
  }
}

// ---- LN + leaky -> influence(bf16); residual hi/lo + norms ----
__global__ __launch_bounds__(256) void ln_residual(
    const float* __restrict__ h, const float* __restrict__ g, const float* __restrict__ be,
    const float* __restrict__ z, const float* __restrict__ gRaw,
    __hip_bfloat16* __restrict__ infl, float* __restrict__ rn,
    __hip_bfloat16* __restrict__ rH, __hip_bfloat16* __restrict__ rL) {
  __shared__ float sred[4];
  const int row = blockIdx.x, t = threadIdx.x;
  const size_t base = (size_t)row * KD;
  float h0 = h[base + t], h1 = h[base + t + 256];
  float m = block_sum(h0 + h1, sred) * (1.0f / 512.0f);
  float d0 = h0 - m, d1 = h1 - m;
  float var = block_sum(d0 * d0 + d1 * d1, sred) * (1.0f / 512.0f);
  float sq = sqrtf(var + 1e-5f);
  float gc = sigmoidf_(gRaw[0]);
  float v0 = d0 / sq * g[t] + be[t];
  float v1 = d1 / sq * g[t + 256] + be[t + 256];
  v0 = v0 > 0.0f ? v0 : 0.1f * v0;
  v1 = v1 > 0.0f ? v1 : 0.1f * v1;
  infl[base + t] = __float2bfloat16(v0);
  infl[base + t + 256] = __float2bfloat16(v1);
  float zf0 = z[(size_t)row * 1024 + 512 + t];
  float zf1 = z[(size_t)row * 1024 + 512 + t + 256];
  float r0 = zf0 - gc * v0, r1 = zf1 - gc * v1;
  __hip_bfloat16 hh, ll;
  split_bf16(r0, &hh, &ll);
  rH[base + t] = hh; rL[base + t] = ll;
  split_bf16(r1, &hh, &ll);
  rH[base + t + 256] = hh; rL[base + t + 256] = ll;
  float rs = block_sum(r0 * r0 + r1 * r1, sred);
  if (t == 0) rn[row] = rs;
}

// ---- LN+leaky on h2, gather q_c/q_f, outputs + loss partials ----
__global__ __launch_bounds__(256) void finalize(
    const float* __restrict__ h, const float* __restrict__ g, const float* __restrict__ be,
    const __hip_bfloat16* __restrict__ infl,
    const unsigned long long* __restrict__ amc, const unsigned long long* __restrict__ amf,
    const float* __restrict__ z, const float* __restrict__ ce, const float* __restrict__ fe,
    const float* __restrict__ gcRaw, const float* __restrict__ gfRaw,
    float* __restrict__ out, float* __restrict__ lossp) {
  __shared__ float sred[4];
  const int row = blockIdx.x, t = threadIdx.x;
  const size_t base = (size_t)row * KD;
  float h0 = h[base + t], h1 = h[base + t + 256];
  float m = block_sum(h0 + h1, sred) * (1.0f / 512.0f);
  float d0 = h0 - m, d1 = h1 - m;
  float var = block_sum(d0 * d0 + d1 * d1, sred) * (1.0f / 512.0f);
  float sq = sqrtf(var + 1e-5f);
  float fb0 = d0 / sq * g[t] + be[t];
  float fb1 = d1 / sq * g[t + 256] + be[t + 256];
  fb0 = fb0 > 0.0f ? fb0 : 0.1f * fb0;
  fb1 = fb1 > 0.0f ? fb1 : 0.1f * fb1;
  float gc = sigmoidf_(gcRaw[0]);
  float gf = sigmoidf_(gfRaw[0]);
  unsigned ic = (unsigned)(amc[row] & 0xffffffffULL);
  unsigned ifx = (unsigned)(amf[row] & 0xffffffffULL);
  float loc = 0.0f;
#pragma unroll
  for (int j = 0; j < 2; ++j) {
    int c = t + j * 256;
    float fb = j ? fb1 : fb0;
    float qc = ce[(size_t)ic * KD + c];
    float qf = fe[(size_t)ifx * KD + c];
    float zc = z[(size_t)row * 1024 + c];
    float zf = z[(size_t)row * 1024 + 512 + c];
    float fl = __bfloat162float(infl[base + c]);
    out[(size_t)row * 1024 + c] = qc + 0.1f * gf * fb;
    out[(size_t)row * 1024 + 512 + c] = qf + gc * fl;
    float dc = qc - zc;
    float res = zf - gc * fl;
    float df = qf - res;
    loc += dc * dc + df * df;
  }
  float ls = block_sum(loc, sred);
  if (t == 0) atomicAdd(lossp, ls);
}

__global__ void loss_write(const float* __restrict__ lossp, float* __restrict__ out) {
  out[0] = 1.25f * lossp[0] / (8192.0f * 512.0f);
}

extern "C" void kernel_launch(void* const* d_in, const int* in_sizes, int n_in,
                              void* d_out, int out_size, void* d_ws, size_t ws_size,
                              hipStream_t stream) {
  const float* z      = (const float*)d_in[0];
  const float* ce     = (const float*)d_in[1];
  const float* fe     = (const float*)d_in[2];
  const float* w_c2f  = (const float*)d_in[3];
  const float* b_c2f  = (const float*)d_in[4];
  const float* g_c2f  = (const float*)d_in[5];
  const float* be_c2f = (const float*)d_in[6];
  const float* w_f2c  = (const float*)d_in[7];
  const float* b_f2c  = (const float*)d_in[8];
  const float* g_f2c  = (const float*)d_in[9];
  const float* be_f2c = (const float*)d_in[10];
  const float* gcRaw  = (const float*)d_in[11];
  const float* gfRaw  = (const float*)d_in[12];
  float* out = (float*)d_out;
  char* ws = (char*)d_ws;

  float* cn = (float*)(ws + OFF_CN);
  float* fn = (float*)(ws + OFF_FN);
  float* zn = (float*)(ws + OFF_ZN);
  float* rn = (float*)(ws + OFF_RN);
  float* lossp = (float*)(ws + OFF_LOSS);
  unsigned long long* amc = (unsigned long long*)(ws + OFF_AMC);
  unsigned long long* amf = (unsigned long long*)(ws + OFF_AMF);
  __hip_bfloat16* ceH = (__hip_bfloat16*)(ws + OFF_CEH);
  __hip_bfloat16* ceL = (__hip_bfloat16*)(ws + OFF_CEL);
  __hip_bfloat16* feH = (__hip_bfloat16*)(ws + OFF_FEH);
  __hip_bfloat16* feL = (__hip_bfloat16*)(ws + OFF_FEL);
  __hip_bfloat16* zcH = (__hip_bfloat16*)(ws + OFF_ZCH);
  __hip_bfloat16* zcL = (__hip_bfloat16*)(ws + OFF_ZCL);
  __hip_bfloat16* rH  = (__hip_bfloat16*)(ws + OFF_RH);
  __hip_bfloat16* rL  = (__hip_bfloat16*)(ws + OFF_RL);
  __hip_bfloat16* w1H = (__hip_bfloat16*)(ws + OFF_W1H);
  __hip_bfloat16* w1L = (__hip_bfloat16*)(ws + OFF_W1L);
  __hip_bfloat16* w2H = (__hip_bfloat16*)(ws + OFF_W2H);
  __hip_bfloat16* w2L = (__hip_bfloat16*)(ws + OFF_W2L);
  float* h = (float*)(ws + OFF_H);
  __hip_bfloat16* infl = (__hip_bfloat16*)(ws + OFF_INFL);

  // init argmin keys (coarse+fine contiguous) to u64 max
  hipMemsetAsync(ws + OFF_AMC, 0xFF, 131072, stream);

  // norms + hi/lo splits; zero loss
  prep<<<21504, 256, 0, stream>>>(ce, fe, z, w_c2f, w_f2c, cn, fn, zn,
                                  ceH, ceL, feH, feL, zcH, zcL,
                                  w1H, w1L, w2H, w2L, lossp);

  // coarse VQ: 8192 x 4096, argmin
  gemm5<<<dim3(32, 64), 256, 0, stream>>>(zcH, zcL, nullptr, ceH, ceL,
                                          zn, cn, amc, nullptr, nullptr, 0);

  // MLP1: h = gather(ce, amc) @ w_c2f^T + b
  gemm5<<<dim3(4, 64), 256, 0, stream>>>(ceH, ceL, amc, w1H, w1L,
                                         nullptr, nullptr, nullptr, b_c2f, h, 1);

  // LN + leaky -> influence (bf16); residual hi/lo + norms
  ln_residual<<<8192, 256, 0, stream>>>(h, g_c2f, be_c2f, z, gcRaw, infl, rn, rH, rL);

  // fine VQ: 8192 x 8192, argmin
  gemm5<<<dim3(64, 64), 256, 0, stream>>>(rH, rL, nullptr, feH, feL,
                                          rn, fn, amf, nullptr, nullptr, 0);

  // MLP2: h = gather(fe, amf) @ w_f2c^T + b
  gemm5<<<dim3(4, 64), 256, 0, stream>>>(feH, feL, amf, w2H, w2L,
                                         nullptr, nullptr, nullptr, b_f2c, h, 1);

  // outputs + loss
  finalize<<<8192, 256, 0, stream>>>(h, g_f2c, be_f2c, infl, amc, amf, z, ce, fe,
                                     gcRaw, gfRaw, out, lossp);
  loss_write<<<1, 1, 0, stream>>>(lossp, out + (size_t)8192 * 1024);
}

// Round 6
// 637.907 us; speedup vs baseline: 1.3375x; 1.3375x over previous
//
#include <hip/hip_runtime.h>
#include <hip/hip_bf16.h>
#include <cstdint>
#include <cstddef>

#define KD 512

// ---- workspace byte offsets ----
#define OFF_CN   0u           // 4096 f32 coarse codebook norms
#define OFF_FN   16384u       // 8192 f32 fine codebook norms
#define OFF_ZN   49152u       // 8192 f32 z-coarse row norms
#define OFF_RN   81920u       // 8192 f32 residual row norms
#define OFF_LOSS 114688u      // 1 f32 loss accumulator
#define OFF_AMC  114944u      // 8192 u64 coarse argmin keys
#define OFF_AMF  180480u      // 8192 u64 fine argmin keys
#define OFF_CEH  246016u      // 4096x512 bf16 coarse emb hi (FRAG layout)
#define OFF_CEL  4440320u     // 4096x512 bf16 coarse emb lo (FRAG layout)
#define OFF_FEH  8634624u     // 8192x512 bf16 fine emb hi (FRAG layout)
#define OFF_FEL  17023232u    // 8192x512 bf16 fine emb lo (FRAG layout)
#define OFF_ZCH  25411840u    // 8192x512 bf16 z-coarse hi (row-major)
#define OFF_ZCL  33800448u
#define OFF_RH   42189056u    // 8192x512 bf16 residual hi (row-major)
#define OFF_RL   50577664u
#define OFF_W1H  58966272u    // 512x512 bf16 w_c2f hi (row-major)
#define OFF_W1L  59490560u
#define OFF_W2H  60014848u
#define OFF_W2L  60539136u
#define OFF_H    61063424u    // 8192x512 f32
#define OFF_INFL 77840640u    // 8192x512 bf16
// total = 86,229,248 bytes

// frag layout: 16B chunk index = ((row>>4)*16 + (k>>5))*64 + lane,
// lane = (row&15) | (((k>>3)&3)<<4); chunk holds elems k..k+7 of row.

typedef __attribute__((ext_vector_type(8))) short bf16x8;
typedef __attribute__((ext_vector_type(4))) float f32x4;

__device__ __forceinline__ bf16x8 as_bf16x8(int4 v) {
  union { int4 i; bf16x8 b; } u; u.i = v; return u.b;
}

__device__ __forceinline__ float block_sum(float v, float* sred) {
#pragma unroll
  for (int off = 32; off > 0; off >>= 1) v += __shfl_down(v, off, 64);
  if ((threadIdx.x & 63) == 0) sred[threadIdx.x >> 6] = v;
  __syncthreads();
  float r = sred[0] + sred[1] + sred[2] + sred[3];
  __syncthreads();
  return r;
}

__device__ __forceinline__ float sigmoidf_(float x) { return 1.0f / (1.0f + expf(-x)); }

__device__ __forceinline__ void split_bf16(float v, __hip_bfloat16* hi, __hip_bfloat16* lo) {
  __hip_bfloat16 h = __float2bfloat16(v);
  *hi = h;
  *lo = __float2bfloat16(v - __bfloat162float(h));
}

// ---- prep: norms + splits. Codebooks -> FRAG layout; zc/w -> row-major. ----
__global__ __launch_bounds__(256) void prep(
    const float* __restrict__ ce, const float* __restrict__ fe, const float* __restrict__ z,
    const float* __restrict__ w1, const float* __restrict__ w2,
    float* __restrict__ cn, float* __restrict__ fn, float* __restrict__ zn,
    __hip_bfloat16* __restrict__ ceH, __hip_bfloat16* __restrict__ ceL,
    __hip_bfloat16* __restrict__ feH, __hip_bfloat16* __restrict__ feL,
    __hip_bfloat16* __restrict__ zcH, __hip_bfloat16* __restrict__ zcL,
    __hip_bfloat16* __restrict__ w1H, __hip_bfloat16* __restrict__ w1L,
    __hip_bfloat16* __restrict__ w2H, __hip_bfloat16* __restrict__ w2L,
    float* __restrict__ lossp) {
  __shared__ float sred[4];
  const int b = blockIdx.x, t = threadIdx.x;
  const float* src;
  float* nd = nullptr;
  __hip_bfloat16 *dh, *dl;
  int fragMode = 0;
  size_t row;
  if (b < 4096) {
    row = b; src = ce + row * KD; nd = cn + row; dh = ceH; dl = ceL; fragMode = 1;
  } else if (b < 12288) {
    row = b - 4096; src = fe + row * KD; nd = fn + row; dh = feH; dl = feL; fragMode = 1;
  } else if (b < 20480) {
    row = b - 12288; src = z + row * 1024; nd = zn + row; dh = zcH; dl = zcL;
  } else if (b < 20992) {
    row = b - 20480; src = w1 + row * KD; dh = w1H; dl = w1L;
  } else {
    row = b - 20992; src = w2 + row * KD; dh = w2H; dl = w2L;
  }
  float acc = 0.0f;
  if (fragMode) {
    float v0 = src[t], v1 = src[t + 256];
    acc = v0 * v0 + v1 * v1;
  } else {
#pragma unroll
    for (int j = 0; j < 2; ++j) {
      int c = t + j * 256;
      float v = src[c];
      acc += v * v;
      __hip_bfloat16 h, l;
      split_bf16(v, &h, &l);
      dh[row * KD + c] = h;
      dl[row * KD + c] = l;
    }
  }
  if (nd) {
    float s = block_sum(acc, sred);
    if (t == 0) nd[0] = s;
  } else {
    __syncthreads();  // keep barrier count uniform (block_sum has syncs)
    __syncthreads();
  }
  if (fragMode && t < 64) {
    // thread t: elems [8t, 8t+8) -> one 16B chunk each for hi/lo
    union { int4 i; __hip_bfloat16 s[8]; } ph, pl;
#pragma unroll
    for (int j = 0; j < 8; ++j) {
      float v = src[8 * t + j];
      split_bf16(v, &ph.s[j], &pl.s[j]);
    }
    const int chunkIdx = (int)(((row >> 4) * 16 + (t >> 2)) * 64 +
                               ((size_t)((t & 3) << 4) | (row & 15)));
    ((int4*)dh)[chunkIdx] = ph.i;
    ((int4*)dl)[chunkIdx] = pl.i;
  }
  if (b == 20480 && t == 0) lossp[0] = 0.0f;
}

// ---- VQ: A = codebook (frag-layout, direct global), B = queries (LDS dbuf) ----
// 128 codes x 128 queries per block. dot3 = Ah*Bh + Ah*Bl + Al*Bh.
// Epilogue: per-query argmin over codes -> atomicMin u64 key.
__global__ __launch_bounds__(256) void vq6(
    const int4* __restrict__ AfH, const int4* __restrict__ AfL,  // codebook frag
    const __hip_bfloat16* __restrict__ Bh, const __hip_bfloat16* __restrict__ Bl,  // queries rm
    const float* __restrict__ qn, const float* __restrict__ cn,  // query / code norms
    unsigned long long* __restrict__ amin) {
  __shared__ __align__(16) __hip_bfloat16 sBh[2][128 * 32];
  __shared__ __align__(16) __hip_bfloat16 sBl[2][128 * 32];
  const int t = threadIdx.x;
  const int w = t >> 6, l = t & 63;
  const int rowTile = blockIdx.y << 7;  // codes
  const int colTile = blockIdx.x << 7;  // queries
  const int wr = (w >> 1) << 6;
  const int wc = (w & 1) << 6;

  // B staging (queries): thread t covers query rows srow, srow+64; 16B block sb
  const int srow = t >> 2;
  const int sb = t & 3;
  const int skE = sb << 3;
  const int swz = (sb ^ ((srow >> 1) & 3)) << 3;
  const int wOff0 = (srow << 5) + swz;
  const int wOff1 = ((srow + 64) << 5) + swz;
  const size_t br0 = (size_t)(colTile + srow) * KD;
  const size_t br1 = (size_t)(colTile + 64 + srow) * KD;

  const int fr = l & 15;
  const int q = l >> 4;

  // A frag bases (int4 units): ((rowBase>>4)*16 + kChunk)*64 + lane
  int aB[4];
#pragma unroll
  for (int mt = 0; mt < 4; ++mt)
    aB[mt] = (((rowTile + wr + (mt << 4)) >> 4) << 10) + l;

  f32x4 acc[4][4];
#pragma unroll
  for (int i = 0; i < 4; ++i)
#pragma unroll
    for (int j = 0; j < 4; ++j) acc[i][j] = (f32x4){0.f, 0.f, 0.f, 0.f};

  // prologue: chunk 0
  int4 rBh0 = *(const int4*)(Bh + br0 + skE);
  int4 rBh1 = *(const int4*)(Bh + br1 + skE);
  int4 rBl0 = *(const int4*)(Bl + br0 + skE);
  int4 rBl1 = *(const int4*)(Bl + br1 + skE);
  int4 aH[4], aL[4];
#pragma unroll
  for (int mt = 0; mt < 4; ++mt) {
    aH[mt] = AfH[aB[mt]];
    aL[mt] = AfL[aB[mt]];
  }

  int p = 0;
  for (int kk = 0; kk < KD; kk += 32) {
    // write current B regs to buf[p] (prev iter's reads were from buf[p^1])
    *(int4*)(sBh[p] + wOff0) = rBh0; *(int4*)(sBh[p] + wOff1) = rBh1;
    *(int4*)(sBl[p] + wOff0) = rBl0; *(int4*)(sBl[p] + wOff1) = rBl1;
    __syncthreads();  // single barrier per chunk (dbuf)

    // current A operands (regs loaded last iter)
    bf16x8 afh[4], afl[4];
#pragma unroll
    for (int mt = 0; mt < 4; ++mt) {
      afh[mt] = as_bf16x8(aH[mt]);
      afl[mt] = as_bf16x8(aL[mt]);
    }

    // prefetch next chunk (wraps harmlessly at end)
    const int nkc = (kk + 32 < KD) ? ((kk >> 5) + 1) : 0;
    const int nkE = nkc << 5;
    rBh0 = *(const int4*)(Bh + br0 + nkE + skE);
    rBh1 = *(const int4*)(Bh + br1 + nkE + skE);
    rBl0 = *(const int4*)(Bl + br0 + nkE + skE);
    rBl1 = *(const int4*)(Bl + br1 + nkE + skE);
#pragma unroll
    for (int mt = 0; mt < 4; ++mt) {
      aH[mt] = AfH[aB[mt] + (nkc << 6)];
      aL[mt] = AfL[aB[mt] + (nkc << 6)];
    }

    // B frags from LDS buf[p] (swizzled, conflict-free)
    bf16x8 bfh[4], bfl[4];
#pragma unroll
    for (int nt = 0; nt < 4; ++nt) {
      const int rB = wc + (nt << 4) + fr;
      const int o = (rB << 5) + ((q ^ ((rB >> 1) & 3)) << 3);
      bfh[nt] = *(const bf16x8*)(sBh[p] + o);
      bfl[nt] = *(const bf16x8*)(sBl[p] + o);
    }
#pragma unroll
    for (int mt = 0; mt < 4; ++mt)
#pragma unroll
      for (int nt = 0; nt < 4; ++nt) {
        acc[mt][nt] = __builtin_amdgcn_mfma_f32_16x16x32_bf16(afh[mt], bfh[nt], acc[mt][nt], 0, 0, 0);
        acc[mt][nt] = __builtin_amdgcn_mfma_f32_16x16x32_bf16(afh[mt], bfl[nt], acc[mt][nt], 0, 0, 0);
        acc[mt][nt] = __builtin_amdgcn_mfma_f32_16x16x32_bf16(afl[mt], bfh[nt], acc[mt][nt], 0, 0, 0);
      }
    p ^= 1;
  }

  // epilogue: C rows = codes, cols = queries. lane: query = ...+nt*16+fr,
  // codes = ...+mt*16+quad*4+reg. Per-query min over 16 local + quad reduce.
#pragma unroll
  for (int nt = 0; nt < 4; ++nt) {
    const int query = colTile + wc + (nt << 4) + fr;
    const float xn = qn[query];
    unsigned long long key = ~0ULL;
#pragma unroll
    for (int mt = 0; mt < 4; ++mt) {
#pragma unroll
      for (int reg = 0; reg < 4; ++reg) {
        const int code = rowTile + wr + (mt << 4) + (q << 2) + reg;
        float d = (xn + cn[code]) - 2.0f * acc[mt][nt][reg];
        unsigned ub = __float_as_uint(d);
        ub = (ub & 0x80000000u) ? ~ub : (ub | 0x80000000u);
        unsigned long long k2 = ((unsigned long long)ub << 32) | (unsigned long long)(unsigned)code;
        if (k2 < key) key = k2;
      }
    }
    unsigned long long o1 = __shfl_xor(key, 16, 64);
    if (o1 < key) key = o1;
    unsigned long long o2 = __shfl_xor(key, 32, 64);
    if (o2 < key) key = o2;
    if (l < 16) atomicMin(amin + colTile + wc + (nt << 4) + l, key);
  }
}

// ---- MLP GEMM: A = gathered codebook rows (frag layout), B = weights (rm) ----
// h[row][col] = sum_k code[g(row)][k] * w[col][k] + bias[col], bf16x3 MFMA.
__global__ __launch_bounds__(256) void mlp6(
    const int4* __restrict__ AfH, const int4* __restrict__ AfL,
    const unsigned long long* __restrict__ gather,
    const __hip_bfloat16* __restrict__ Bh, const __hip_bfloat16* __restrict__ Bl,
    const float* __restrict__ bias, float* __restrict__ C) {
  __shared__ __align__(16) __hip_bfloat16 sAh[128 * 32];
  __shared__ __align__(16) __hip_bfloat16 sAl[128 * 32];
  __shared__ __align__(16) __hip_bfloat16 sBh[128 * 32];
  __shared__ __align__(16) __hip_bfloat16 sBl[128 * 32];
  const int t = threadIdx.x;
  const int w = t >> 6, l = t & 63;
  const int rowTile = blockIdx.y << 7;
  const int colTile = blockIdx.x << 7;
  const int wr = (w >> 1) << 6;
  const int wc = (w & 1) << 6;

  const int srow = t >> 2;
  const int sb = t & 3;
  const int skE = sb << 3;
  const int swz = (sb ^ ((srow >> 1) & 3)) << 3;
  const int wOff0 = (srow << 5) + swz;
  const int wOff1 = ((srow + 64) << 5) + swz;

  // gathered A chunk bases (int4 units): (idx>>4)*1024 + (sb<<4) + (idx&15); +64/chunk
  unsigned i0 = ((const unsigned*)gather)[2 * (rowTile + srow)];
  unsigned i1 = ((const unsigned*)gather)[2 * (rowTile + 64 + srow)];
  const int a0 = (int)((i0 >> 4) << 10) + (sb << 4) + (int)(i0 & 15);
  const int a1 = (int)((i1 >> 4) << 10) + (sb << 4) + (int)(i1 & 15);
  const size_t br0 = (size_t)(colTile + srow) * KD;
  const size_t br1 = (size_t)(colTile + 64 + srow) * KD;

  const int fr = l & 15;
  const int q = l >> 4;
  const int foff = (q ^ ((fr >> 1) & 3)) << 3;

  f32x4 acc[4][4];
#pragma unroll
  for (int i = 0; i < 4; ++i)
#pragma unroll
    for (int j = 0; j < 4; ++j) acc[i][j] = (f32x4){0.f, 0.f, 0.f, 0.f};

  for (int kk = 0; kk < KD; kk += 32) {
    const int kc64 = (kk >> 5) << 6;
    int4 vAh0 = AfH[a0 + kc64];
    int4 vAh1 = AfH[a1 + kc64];
    int4 vAl0 = AfL[a0 + kc64];
    int4 vAl1 = AfL[a1 + kc64];
    int4 vBh0 = *(const int4*)(Bh + br0 + kk + skE);
    int4 vBh1 = *(const int4*)(Bh + br1 + kk + skE);
    int4 vBl0 = *(const int4*)(Bl + br0 + kk + skE);
    int4 vBl1 = *(const int4*)(Bl + br1 + kk + skE);
    __syncthreads();
    *(int4*)(sAh + wOff0) = vAh0; *(int4*)(sAh + wOff1) = vAh1;
    *(int4*)(sAl + wOff0) = vAl0; *(int4*)(sAl + wOff1) = vAl1;
    *(int4*)(sBh + wOff0) = vBh0; *(int4*)(sBh + wOff1) = vBh1;
    *(int4*)(sBl + wOff0) = vBl0; *(int4*)(sBl + wOff1) = vBl1;
    __syncthreads();

    bf16x8 afh[4], afl[4], bfh[4], bfl[4];
#pragma unroll
    for (int mt = 0; mt < 4; ++mt) {
      const int rA = wr + (mt << 4) + fr;
      const int o = (rA << 5) + ((q ^ ((rA >> 1) & 3)) << 3);
      afh[mt] = *(const bf16x8*)(sAh + o);
      afl[mt] = *(const bf16x8*)(sAl + o);
    }
#pragma unroll
    for (int nt = 0; nt < 4; ++nt) {
      const int rB = wc + (nt << 4) + fr;
      const int o = (rB << 5) + ((q ^ ((rB >> 1) & 3)) << 3);
      bfh[nt] = *(const bf16x8*)(sBh + o);
      bfl[nt] = *(const bf16x8*)(sBl + o);
    }
#pragma unroll
    for (int mt = 0; mt < 4; ++mt)
#pragma unroll
      for (int nt = 0; nt < 4; ++nt) {
        acc[mt][nt] = __builtin_amdgcn_mfma_f32_16x16x32_bf16(afh[mt], bfh[nt], acc[mt][nt], 0, 0, 0);
        acc[mt][nt] = __builtin_amdgcn_mfma_f32_16x16x32_bf16(afh[mt], bfl[nt], acc[mt][nt], 0, 0, 0);
        acc[mt][nt] = __builtin_amdgcn_mfma_f32_16x16x32_bf16(afl[mt], bfh[nt], acc[mt][nt], 0, 0, 0);
      }
  }

  const int quad = l >> 4;
#pragma unroll
  for (int mt = 0; mt < 4; ++mt) {
#pragma unroll
    for (int reg = 0; reg < 4; ++reg) {
      const int row = rowTile + wr + (mt << 4) + (quad << 2) + reg;
#pragma unroll
      for (int nt = 0; nt < 4; ++nt) {
        const int col = colTile + wc + (nt << 4) + fr;
        C[(size_t)row * KD + col] = acc[mt][nt][reg] + bias[col];
      }
    }
  }
}

// ---- LN + leaky -> influence(bf16); residual hi/lo (row-major) + norms ----
__global__ __launch_bounds__(256) void ln_residual(
    const float* __restrict__ h, const float* __restrict__ g, const float* __restrict__ be,
    const float* __restrict__ z, const float* __restrict__ gRaw,
    __hip_bfloat16* __restrict__ infl, float* __restrict__ rn,
    __hip_bfloat16* __restrict__ rH, __hip_bfloat16* __restrict__ rL) {
  __shared__ float sred[4];
  const int row = blockIdx.x, t = threadIdx.x;
  const size_t base = (size_t)row * KD;
  float h0 = h[base + t], h1 = h[base + t + 256];
  float m = block_sum(h0 + h1, sred) * (1.0f / 512.0f);
  float d0 = h0 - m, d1 = h1 - m;
  float var = block_sum(d0 * d0 + d1 * d1, sred) * (1.0f / 512.0f);
  float sq = sqrtf(var + 1e-5f);
  float gc = sigmoidf_(gRaw[0]);
  float v0 = d0 / sq * g[t] + be[t];
  float v1 = d1 / sq * g[t + 256] + be[t + 256];
  v0 = v0 > 0.0f ? v0 : 0.1f * v0;
  v1 = v1 > 0.0f ? v1 : 0.1f * v1;
  infl[base + t] = __float2bfloat16(v0);
  infl[base + t + 256] = __float2bfloat16(v1);
  float zf0 = z[(size_t)row * 1024 + 512 + t];
  float zf1 = z[(size_t)row * 1024 + 512 + t + 256];
  float r0 = zf0 - gc * v0, r1 = zf1 - gc * v1;
  __hip_bfloat16 hh, ll;
  split_bf16(r0, &hh, &ll);
  rH[base + t] = hh; rL[base + t] = ll;
  split_bf16(r1, &hh, &ll);
  rH[base + t + 256] = hh; rL[base + t + 256] = ll;
  float rs = block_sum(r0 * r0 + r1 * r1, sred);
  if (t == 0) rn[row] = rs;
}

// ---- LN+leaky on h2, gather q_c/q_f, outputs + loss partials ----
__global__ __launch_bounds__(256) void finalize(
    const float* __restrict__ h, const float* __restrict__ g, const float* __restrict__ be,
    const __hip_bfloat16* __restrict__ infl,
    const unsigned long long* __restrict__ amc, const unsigned long long* __restrict__ amf,
    const float* __restrict__ z, const float* __restrict__ ce, const float* __restrict__ fe,
    const float* __restrict__ gcRaw, const float* __restrict__ gfRaw,
    float* __restrict__ out, float* __restrict__ lossp) {
  __shared__ float sred[4];
  const int row = blockIdx.x, t = threadIdx.x;
  const size_t base = (size_t)row * KD;
  float h0 = h[base + t], h1 = h[base + t + 256];
  float m = block_sum(h0 + h1, sred) * (1.0f / 512.0f);
  float d0 = h0 - m, d1 = h1 - m;
  float var = block_sum(d0 * d0 + d1 * d1, sred) * (1.0f / 512.0f);
  float sq = sqrtf(var + 1e-5f);
  float fb0 = d0 / sq * g[t] + be[t];
  float fb1 = d1 / sq * g[t + 256] + be[t + 256];
  fb0 = fb0 > 0.0f ? fb0 : 0.1f * fb0;
  fb1 = fb1 > 0.0f ? fb1 : 0.1f * fb1;
  float gc = sigmoidf_(gcRaw[0]);
  float gf = sigmoidf_(gfRaw[0]);
  unsigned ic = (unsigned)(amc[row] & 0xffffffffULL);
  unsigned ifx = (unsigned)(amf[row] & 0xffffffffULL);
  float loc = 0.0f;
#pragma unroll
  for (int j = 0; j < 2; ++j) {
    int c = t + j * 256;
    float fb = j ? fb1 : fb0;
    float qc = ce[(size_t)ic * KD + c];
    float qf = fe[(size_t)ifx * KD + c];
    float zc = z[(size_t)row * 1024 + c];
    float zf = z[(size_t)row * 1024 + 512 + c];
    float fl = __bfloat162float(infl[base + c]);
    out[(size_t)row * 1024 + c] = qc + 0.1f * gf * fb;
    out[(size_t)row * 1024 + 512 + c] = qf + gc * fl;
    float dc = qc - zc;
    float res = zf - gc * fl;
    float df = qf - res;
    loc += dc * dc + df * df;
  }
  float ls = block_sum(loc, sred);
  if (t == 0) atomicAdd(lossp, ls);
}

__global__ void loss_write(const float* __restrict__ lossp, float* __restrict__ out) {
  out[0] = 1.25f * lossp[0] / (8192.0f * 512.0f);
}

extern "C" void kernel_launch(void* const* d_in, const int* in_sizes, int n_in,
                              void* d_out, int out_size, void* d_ws, size_t ws_size,
                              hipStream_t stream) {
  const float* z      = (const float*)d_in[0];
  const float* ce     = (const float*)d_in[1];
  const float* fe     = (const float*)d_in[2];
  const float* w_c2f  = (const float*)d_in[3];
  const float* b_c2f  = (const float*)d_in[4];
  const float* g_c2f  = (const float*)d_in[5];
  const float* be_c2f = (const float*)d_in[6];
  const float* w_f2c  = (const float*)d_in[7];
  const float* b_f2c  = (const float*)d_in[8];
  const float* g_f2c  = (const float*)d_in[9];
  const float* be_f2c = (const float*)d_in[10];
  const float* gcRaw  = (const float*)d_in[11];
  const float* gfRaw  = (const float*)d_in[12];
  float* out = (float*)d_out;
  char* ws = (char*)d_ws;

  float* cn = (float*)(ws + OFF_CN);
  float* fn = (float*)(ws + OFF_FN);
  float* zn = (float*)(ws + OFF_ZN);
  float* rn = (float*)(ws + OFF_RN);
  float* lossp = (float*)(ws + OFF_LOSS);
  unsigned long long* amc = (unsigned long long*)(ws + OFF_AMC);
  unsigned long long* amf = (unsigned long long*)(ws + OFF_AMF);
  __hip_bfloat16* ceH = (__hip_bfloat16*)(ws + OFF_CEH);
  __hip_bfloat16* ceL = (__hip_bfloat16*)(ws + OFF_CEL);
  __hip_bfloat16* feH = (__hip_bfloat16*)(ws + OFF_FEH);
  __hip_bfloat16* feL = (__hip_bfloat16*)(ws + OFF_FEL);
  __hip_bfloat16* zcH = (__hip_bfloat16*)(ws + OFF_ZCH);
  __hip_bfloat16* zcL = (__hip_bfloat16*)(ws + OFF_ZCL);
  __hip_bfloat16* rH  = (__hip_bfloat16*)(ws + OFF_RH);
  __hip_bfloat16* rL  = (__hip_bfloat16*)(ws + OFF_RL);
  __hip_bfloat16* w1H = (__hip_bfloat16*)(ws + OFF_W1H);
  __hip_bfloat16* w1L = (__hip_bfloat16*)(ws + OFF_W1L);
  __hip_bfloat16* w2H = (__hip_bfloat16*)(ws + OFF_W2H);
  __hip_bfloat16* w2L = (__hip_bfloat16*)(ws + OFF_W2L);
  float* h = (float*)(ws + OFF_H);
  __hip_bfloat16* infl = (__hip_bfloat16*)(ws + OFF_INFL);

  // init argmin keys (coarse+fine contiguous) to u64 max
  hipMemsetAsync(ws + OFF_AMC, 0xFF, 131072, stream);

  // norms + splits (codebooks -> frag layout); zero loss
  prep<<<21504, 256, 0, stream>>>(ce, fe, z, w_c2f, w_f2c, cn, fn, zn,
                                  ceH, ceL, feH, feL, zcH, zcL,
                                  w1H, w1L, w2H, w2L, lossp);

  // coarse VQ: 4096 codes (A, frag) x 8192 queries (B, LDS)
  vq6<<<dim3(64, 32), 256, 0, stream>>>((const int4*)ceH, (const int4*)ceL,
                                        zcH, zcL, zn, cn, amc);

  // MLP1: h = gather(ce, amc) @ w_c2f^T + b
  mlp6<<<dim3(4, 64), 256, 0, stream>>>((const int4*)ceH, (const int4*)ceL, amc,
                                        w1H, w1L, b_c2f, h);

  // LN + leaky -> influence (bf16); residual hi/lo + norms
  ln_residual<<<8192, 256, 0, stream>>>(h, g_c2f, be_c2f, z, gcRaw, infl, rn, rH, rL);

  // fine VQ: 8192 codes x 8192 queries
  vq6<<<dim3(64, 64), 256, 0, stream>>>((const int4*)feH, (const int4*)feL,
                                        rH, rL, rn, fn, amf);

  // MLP2: h = gather(fe, amf) @ w_f2c^T + b
  mlp6<<<dim3(4, 64), 256, 0, stream>>>((const int4*)feH, (const int4*)feL, amf,
                                        w2H, w2L, b_f2c, h);

  // outputs + loss
  finalize<<<8192, 256, 0, stream>>>(h, g_f2c, be_f2c, infl, amc, amf, z, ce, fe,
                                     gcRaw, gfRaw, out, lossp);
  loss_write<<<1, 1, 0, stream>>>(lossp, out + (size_t)8192 * 1024);
}